// Round 9
// baseline (342.154 us; speedup 1.0000x reference)
//
#include <hip/hip_runtime.h>
#include <hip/hip_bf16.h>

#define B_ 32
#define K_ 4
#define N_ 512
#define F_ 128

typedef __attribute__((ext_vector_type(8))) short short8;
typedef __attribute__((ext_vector_type(4))) short short4v;
typedef __attribute__((ext_vector_type(4))) float float4v;

__device__ __forceinline__ unsigned short f2bf(float x) {
    unsigned int u = __builtin_bit_cast(unsigned int, x);
    u += 0x7FFFu + ((u >> 16) & 1u);
    return (unsigned short)(u >> 16);
}

__device__ __forceinline__ short8 pack8(float4v a, float4v b) {
    short8 r;
    r[0] = (short)f2bf(a[0]); r[1] = (short)f2bf(a[1]);
    r[2] = (short)f2bf(a[2]); r[3] = (short)f2bf(a[3]);
    r[4] = (short)f2bf(b[0]); r[5] = (short)f2bf(b[1]);
    r[6] = (short)f2bf(b[2]); r[7] = (short)f2bf(b[3]);
    return r;
}

// ---------------- k0: weight transposes (tiny) ----------------
__global__ void k0_weights(const float* __restrict__ RW, const float* __restrict__ SW,
                           unsigned short* __restrict__ Wt, unsigned short* __restrict__ SWt) {
    int r = blockIdx.x;   // 0..639
    int m = threadIdx.x;  // 0..127
    if (r < 512) {
        int k = r >> 7, f = r & 127;
        Wt[r * F_ + m] = f2bf(RW[(m * F_ + f) * K_ + k]);
    } else {
        int l = r - 512;
        SWt[l * F_ + m] = f2bf(SW[m * F_ + l]);
    }
}

// ---------------- k1v3: colsum + E->bf16, MLP-staged ----------------
// grid: b(32) x k(4) x isl(16) = 2048 blocks, 256 threads.
// thread t: j8 = (t&63)*8 (8 consecutive cols), rows = isl*32 + (t>>6)*8 .. +8.
// Loads staged 8-deep before any consumption (forces outstanding loads).
__global__ void __launch_bounds__(256)
k1v3_convert(const float* __restrict__ E, float* __restrict__ colsum,
             unsigned short* __restrict__ Ebf) {
    int bid = blockIdx.x;
    int b   = bid >> 6;
    int k   = (bid >> 4) & 3;
    int isl = bid & 15;
    int t   = threadIdx.x;
    int j8  = (t & 63) * 8;
    int r0  = isl * 32 + (t >> 6) * 8;

    const size_t base = ((size_t)((b * K_ + k) * N_ + r0)) * N_ + j8;
    const float* Ep = E + base;
    unsigned short* Op = Ebf + base;

    float4v va[8], vb[8];
    // batch 1: rows 0..3 (8 loads in flight)
#pragma unroll
    for (int r = 0; r < 4; ++r) {
        va[r] = *(const float4v*)(Ep + (size_t)r * N_);
        vb[r] = *(const float4v*)(Ep + (size_t)r * N_ + 4);
    }
    // batch 2: rows 4..7
#pragma unroll
    for (int r = 4; r < 8; ++r) {
        va[r] = *(const float4v*)(Ep + (size_t)r * N_);
        vb[r] = *(const float4v*)(Ep + (size_t)r * N_ + 4);
    }

    float cs[8];
#pragma unroll
    for (int e = 0; e < 8; ++e) cs[e] = 0.f;
#pragma unroll
    for (int r = 0; r < 8; ++r) {
        cs[0] += va[r][0]; cs[1] += va[r][1]; cs[2] += va[r][2]; cs[3] += va[r][3];
        cs[4] += vb[r][0]; cs[5] += vb[r][1]; cs[6] += vb[r][2]; cs[7] += vb[r][3];
        *(short8*)(Op + (size_t)r * N_) = pack8(va[r], vb[r]);
    }

    // block-level reduce over the 4 row-groups sharing each j8, then atomics.
    __shared__ float red[256][9];   // pad to 9: conflict-free
#pragma unroll
    for (int e = 0; e < 8; ++e) red[t][e] = cs[e];
    __syncthreads();
    if (t < 64) {
#pragma unroll
        for (int e = 0; e < 8; ++e) {
            float s = red[t][e] + red[t + 64][e] + red[t + 128][e] + red[t + 192][e];
            atomicAdd(&colsum[b * N_ + t * 8 + e], s);
        }
    }
}

// ---------------- k2v2: Tt[b][c][j] = sum_m Wt[c][m]*H[b][j][m], loads hoisted ----------
__global__ void __launch_bounds__(256)
k2v2_expand(const float* __restrict__ H, const unsigned short* __restrict__ Wt,
            unsigned short* __restrict__ Tt) {
    int bid = blockIdx.x;        // 1024 blocks
    int b  = bid >> 5;
    int ct = (bid >> 2) & 7;
    int jt = bid & 3;
    int lane = threadIdx.x & 63;
    int wv   = threadIdx.x >> 6;
    int c0 = ct * 64 + wv * 16;
    int jbase = jt * 128;
    int lrow = lane & 15, lgrp = lane >> 4;

    float4v acc[8];
#pragma unroll
    for (int i = 0; i < 8; ++i) acc[i] = {0.f, 0.f, 0.f, 0.f};

#pragma unroll
    for (int ms = 0; ms < 4; ++ms) {
        int m0 = ms * 32;
        short8 a = *(const short8*)(Wt + (c0 + lrow) * F_ + m0 + lgrp * 8);
        float4v hv0[8], hv1[8];
#pragma unroll
        for (int cf = 0; cf < 8; ++cf) {
            const float* hp = H + ((size_t)b * N_ + jbase + cf * 16 + lrow) * F_ + m0 + lgrp * 8;
            hv0[cf] = *(const float4v*)hp;
            hv1[cf] = *(const float4v*)(hp + 4);
        }
#pragma unroll
        for (int cf = 0; cf < 8; ++cf) {
            short8 bb = pack8(hv0[cf], hv1[cf]);
            acc[cf] = __builtin_amdgcn_mfma_f32_16x16x32_bf16(a, bb, acc[cf], 0, 0, 0);
        }
    }
#pragma unroll
    for (int cf = 0; cf < 8; ++cf) {
#pragma unroll
        for (int r = 0; r < 4; ++r) {
            int c = c0 + lgrp * 4 + r;
            int j = jbase + cf * 16 + lrow;
            Tt[((size_t)b * 512 + c) * N_ + j] = f2bf(acc[cf][r]);
        }
    }
}

// ---------------- k3v3: rel partials, pipelined, 4-way j-split ----------------
// grid: b(32) x it(8) x jc(4) = 1024 blocks, 512 threads (8 waves: 4 i-sub x 2 f-half).
// K-loop: 16 iters (k 0..3 x js 0..3), j-chunk = jc*128 .. +128.
__global__ void __launch_bounds__(512)
k3v3_rel(const unsigned short* __restrict__ Ebf, const unsigned short* __restrict__ Tt,
         float* __restrict__ relP) {
    int bid = blockIdx.x;
    int b  = bid >> 5;
    int it = (bid >> 2) & 7;
    int jc = bid & 3;
    int lane = threadIdx.x & 63;
    int wv   = threadIdx.x >> 6;
    int i0 = it * 64 + (wv >> 1) * 16;
    int f0 = (wv & 1) * 64;
    int lrow = lane & 15, lgrp = lane >> 4;
    int jbase = jc * 128;

    float4v acc[4];
#pragma unroll
    for (int i = 0; i < 4; ++i) acc[i] = {0.f, 0.f, 0.f, 0.f};

    // iter t: k = t>>2, js = t&3. E k-stride 262144, js-stride 32. T k-stride 65536, cf 8192, js 32.
    const unsigned short* Eb = Ebf + ((size_t)(b * K_) * N_ + (i0 + lrow)) * N_ + jbase + lgrp * 8;
    const unsigned short* Tb = Tt + ((size_t)b * 512 + f0 + lrow) * N_ + jbase + lgrp * 8;

#define EA(t) (const short8*)(Eb + ((t) >> 2) * 262144 + ((t) & 3) * 32)
#define TA(t, cf) (const short8*)(Tb + ((t) >> 2) * 65536 + (cf) * 8192 + ((t) & 3) * 32)

    short8 a0, b00, b01, b02, b03;
    short8 a1, b10, b11, b12, b13;
    a0 = *EA(0); b00 = *TA(0, 0); b01 = *TA(0, 1); b02 = *TA(0, 2); b03 = *TA(0, 3);

    for (int t = 0; t < 16; t += 2) {
        int t1 = t + 1;
        int t2 = (t + 2 < 16) ? t + 2 : 15;  // tail: harmless duplicate load
        a1 = *EA(t1); b10 = *TA(t1, 0); b11 = *TA(t1, 1); b12 = *TA(t1, 2); b13 = *TA(t1, 3);
        acc[0] = __builtin_amdgcn_mfma_f32_16x16x32_bf16(a0, b00, acc[0], 0, 0, 0);
        acc[1] = __builtin_amdgcn_mfma_f32_16x16x32_bf16(a0, b01, acc[1], 0, 0, 0);
        acc[2] = __builtin_amdgcn_mfma_f32_16x16x32_bf16(a0, b02, acc[2], 0, 0, 0);
        acc[3] = __builtin_amdgcn_mfma_f32_16x16x32_bf16(a0, b03, acc[3], 0, 0, 0);
        a0 = *EA(t2); b00 = *TA(t2, 0); b01 = *TA(t2, 1); b02 = *TA(t2, 2); b03 = *TA(t2, 3);
        acc[0] = __builtin_amdgcn_mfma_f32_16x16x32_bf16(a1, b10, acc[0], 0, 0, 0);
        acc[1] = __builtin_amdgcn_mfma_f32_16x16x32_bf16(a1, b11, acc[1], 0, 0, 0);
        acc[2] = __builtin_amdgcn_mfma_f32_16x16x32_bf16(a1, b12, acc[2], 0, 0, 0);
        acc[3] = __builtin_amdgcn_mfma_f32_16x16x32_bf16(a1, b13, acc[3], 0, 0, 0);
    }
#undef EA
#undef TA

    float* dst = relP + (size_t)jc * (B_ * N_ * F_);
#pragma unroll
    for (int cf = 0; cf < 4; ++cf) {
#pragma unroll
        for (int r = 0; r < 4; ++r) {
            int i = i0 + lgrp * 4 + r;
            int f = f0 + cf * 16 + lrow;
            dst[((size_t)b * N_ + i) * F_ + f] = acc[cf][r];
        }
    }
}

// ---------------- k4: epilogue — self-term MFMA + D*(sum of 4 rel partials) + sigmoid ----
// grid: b(32) x it(8) = 256 blocks, 512 threads.
__global__ void __launch_bounds__(512)
k4_epi(const float* __restrict__ relP, const float* __restrict__ H,
       const unsigned short* __restrict__ SWt, const float* __restrict__ colsum,
       float* __restrict__ out) {
    int bid = blockIdx.x;
    int b  = bid >> 3;
    int it = bid & 7;
    int lane = threadIdx.x & 63;
    int wv   = threadIdx.x >> 6;
    int i0 = it * 64 + (wv >> 1) * 16;
    int f0 = (wv & 1) * 64;
    int lrow = lane & 15, lgrp = lane >> 4;

    float4v accS[4];
#pragma unroll
    for (int i = 0; i < 4; ++i) accS[i] = {0.f, 0.f, 0.f, 0.f};

    const float* Hp = H + ((size_t)b * N_ + i0 + lrow) * F_;
#pragma unroll
    for (int ms = 0; ms < 4; ++ms) {
        int m0 = ms * 32;
        const float* hp = Hp + m0 + lgrp * 8;
        float4v h0 = *(const float4v*)hp;
        float4v h1 = *(const float4v*)(hp + 4);
        short8 a = pack8(h0, h1);
#pragma unroll
        for (int cf = 0; cf < 4; ++cf) {
            const unsigned short* sp = SWt + (f0 + cf * 16 + lrow) * F_ + m0 + lgrp * 8;
            short8 bb = *(const short8*)sp;
            accS[cf] = __builtin_amdgcn_mfma_f32_16x16x32_bf16(a, bb, accS[cf], 0, 0, 0);
        }
    }

    float Dv[4];
#pragma unroll
    for (int r = 0; r < 4; ++r) {
        int i = i0 + lgrp * 4 + r;
        Dv[r] = 1.0f / (colsum[b * N_ + i] + (float)K_);
    }
    const size_t S = (size_t)B_ * N_ * F_;
#pragma unroll
    for (int cf = 0; cf < 4; ++cf) {
#pragma unroll
        for (int r = 0; r < 4; ++r) {
            int i = i0 + lgrp * 4 + r;
            int f = f0 + cf * 16 + lrow;
            size_t idx = ((size_t)b * N_ + i) * F_ + f;
            float v = relP[idx] + relP[idx + S] + relP[idx + 2 * S] + relP[idx + 3 * S];
            float x = Dv[r] * v + accS[cf][r];
            out[idx] = 1.0f / (1.0f + __expf(-x));
        }
    }
}

// ================= fallback (validated round-0 kernels) =================
__global__ void k1_colsum(const float* __restrict__ E, float* __restrict__ colsum) {
    int bid = blockIdx.x;
    int b   = bid >> 5;
    int jt  = (bid >> 4) & 1;
    int isl = bid & 15;
    int j   = jt * 256 + threadIdx.x;
    int i0  = isl * 32;
    float s0 = 0.f, s1 = 0.f, s2 = 0.f, s3 = 0.f;
#pragma unroll
    for (int k = 0; k < K_; ++k) {
        const float* p = E + ((size_t)((b * K_ + k) * N_ + i0)) * N_ + j;
#pragma unroll 4
        for (int ii = 0; ii < 32; ii += 4) {
            s0 += p[(ii + 0) * N_];
            s1 += p[(ii + 1) * N_];
            s2 += p[(ii + 2) * N_];
            s3 += p[(ii + 3) * N_];
        }
    }
    atomicAdd(&colsum[b * N_ + j], (s0 + s1) + (s2 + s3));
}

__global__ void __launch_bounds__(512)
k3_fuse(const float* __restrict__ E, const float* __restrict__ H,
        const unsigned short* __restrict__ Tt, const unsigned short* __restrict__ SWt,
        const float* __restrict__ colsum, float* __restrict__ out) {
    int bid = blockIdx.x;
    int b  = bid >> 3;
    int it = bid & 7;
    int lane = threadIdx.x & 63;
    int wv   = threadIdx.x >> 6;
    int i0 = it * 64 + (wv >> 1) * 16;
    int f0 = (wv & 1) * 64;
    int lrow = lane & 15, lgrp = lane >> 4;

    float4v accR[4], accS[4];
#pragma unroll
    for (int i = 0; i < 4; ++i) { accR[i] = {0.f, 0.f, 0.f, 0.f}; accS[i] = {0.f, 0.f, 0.f, 0.f}; }

    for (int k = 0; k < K_; ++k) {
        const float* Eb = E + ((size_t)((b * K_ + k) * N_ + i0 + lrow)) * N_;
        const unsigned short* Tb = Tt + ((size_t)b * 512 + k * 128 + f0) * N_;
#pragma unroll 2
        for (int js = 0; js < 16; ++js) {
            int j0 = js * 32;
            const float* ep = Eb + j0 + lgrp * 8;
            float4v e0 = *(const float4v*)ep;
            float4v e1 = *(const float4v*)(ep + 4);
            short8 a = pack8(e0, e1);
#pragma unroll
            for (int cf = 0; cf < 4; ++cf) {
                const unsigned short* tp = Tb + (size_t)(cf * 16 + lrow) * N_ + j0 + lgrp * 8;
                short8 bb = *(const short8*)tp;
                accR[cf] = __builtin_amdgcn_mfma_f32_16x16x32_bf16(a, bb, accR[cf], 0, 0, 0);
            }
        }
    }
    {
        const float* Hp = H + ((size_t)b * N_ + i0 + lrow) * F_;
#pragma unroll
        for (int ms = 0; ms < 4; ++ms) {
            int m0 = ms * 32;
            const float* hp = Hp + m0 + lgrp * 8;
            float4v h0 = *(const float4v*)hp;
            float4v h1 = *(const float4v*)(hp + 4);
            short8 a = pack8(h0, h1);
#pragma unroll
            for (int cf = 0; cf < 4; ++cf) {
                const unsigned short* sp = SWt + (f0 + cf * 16 + lrow) * F_ + m0 + lgrp * 8;
                short8 bb = *(const short8*)sp;
                accS[cf] = __builtin_amdgcn_mfma_f32_16x16x32_bf16(a, bb, accS[cf], 0, 0, 0);
            }
        }
    }
    float Dv[4];
#pragma unroll
    for (int r = 0; r < 4; ++r) {
        int i = i0 + lgrp * 4 + r;
        Dv[r] = 1.0f / (colsum[b * N_ + i] + (float)K_);
    }
#pragma unroll
    for (int cf = 0; cf < 4; ++cf) {
#pragma unroll
        for (int r = 0; r < 4; ++r) {
            int i = i0 + lgrp * 4 + r;
            int f = f0 + cf * 16 + lrow;
            float x = Dv[r] * accR[cf][r] + accS[cf][r];
            out[((size_t)b * N_ + i) * F_ + f] = 1.0f / (1.0f + __expf(-x));
        }
    }
}

extern "C" void kernel_launch(void* const* d_in, const int* in_sizes, int n_in,
                              void* d_out, int out_size, void* d_ws, size_t ws_size,
                              hipStream_t stream) {
    const float* H  = (const float*)d_in[0];
    const float* E  = (const float*)d_in[1];
    const float* RW = (const float*)d_in[2];
    const float* SW = (const float*)d_in[3];
    float* out = (float*)d_out;

    char* ws = (char*)d_ws;
    unsigned short* Wt  = (unsigned short*)(ws);               // 128 KiB
    unsigned short* SWt = (unsigned short*)(ws + 131072);      //  32 KiB
    float* colsum       = (float*)(ws + 163840);               //  64 KiB
    unsigned short* Tt  = (unsigned short*)(ws + 262144);      //  16 MiB
    unsigned short* Ebf = (unsigned short*)(ws + 17039360);    //  64 MiB
    float* relP         = (float*)(ws + 84148224);             //  32 MiB (4 x 8 MiB)
    const size_t WS_NEED = 117702656ull;

    hipMemsetAsync(colsum, 0, B_ * N_ * sizeof(float), stream);
    k0_weights<<<640, 128, 0, stream>>>(RW, SW, Wt, SWt);

    if (ws_size >= WS_NEED) {
        k1v3_convert<<<2048, 256, 0, stream>>>(E, colsum, Ebf);
        k2v2_expand<<<1024, 256, 0, stream>>>(H, Wt, Tt);
        k3v3_rel<<<1024, 512, 0, stream>>>(Ebf, Tt, relP);
        k4_epi<<<256, 512, 0, stream>>>(relP, H, SWt, colsum, out);
    } else {
        k1_colsum<<<1024, 256, 0, stream>>>(E, colsum);
        k2v2_expand<<<1024, 256, 0, stream>>>(H, Wt, Tt);
        k3_fuse<<<256, 512, 0, stream>>>(E, H, Tt, SWt, colsum, out);
    }
}

// Round 11
// 326.363 us; speedup vs baseline: 1.0484x; 1.0484x over previous
//
#include <hip/hip_runtime.h>
#include <hip/hip_bf16.h>

#define B_ 32
#define K_ 4
#define N_ 512
#define F_ 128

typedef __attribute__((ext_vector_type(8))) short short8;
typedef __attribute__((ext_vector_type(4))) float float4v;

__device__ __forceinline__ unsigned short f2bf(float x) {
    unsigned int u = __builtin_bit_cast(unsigned int, x);
    u += 0x7FFFu + ((u >> 16) & 1u);
    return (unsigned short)(u >> 16);
}

__device__ __forceinline__ short8 pack8(float4v a, float4v b) {
    short8 r;
    r[0] = (short)f2bf(a[0]); r[1] = (short)f2bf(a[1]);
    r[2] = (short)f2bf(a[2]); r[3] = (short)f2bf(a[3]);
    r[4] = (short)f2bf(b[0]); r[5] = (short)f2bf(b[1]);
    r[6] = (short)f2bf(b[2]); r[7] = (short)f2bf(b[3]);
    return r;
}

// ---------------- k0: weight transposes (tiny) ----------------
__global__ void k0_weights(const float* __restrict__ RW, const float* __restrict__ SW,
                           unsigned short* __restrict__ Wt, unsigned short* __restrict__ SWt) {
    int r = blockIdx.x;   // 0..639
    int m = threadIdx.x;  // 0..127
    if (r < 512) {
        int k = r >> 7, f = r & 127;
        Wt[r * F_ + m] = f2bf(RW[(m * F_ + f) * K_ + k]);
    } else {
        int l = r - 512;
        SWt[l * F_ + m] = f2bf(SW[m * F_ + l]);
    }
}

// ---------------- k2v2: Tt[b][c][j] = sum_m Wt[c][m]*H[b][j][m] (validated r9) --------
__global__ void __launch_bounds__(256)
k2v2_expand(const float* __restrict__ H, const unsigned short* __restrict__ Wt,
            unsigned short* __restrict__ Tt) {
    int bid = blockIdx.x;        // 1024 blocks
    int b  = bid >> 5;
    int ct = (bid >> 2) & 7;
    int jt = bid & 3;
    int lane = threadIdx.x & 63;
    int wv   = threadIdx.x >> 6;
    int c0 = ct * 64 + wv * 16;
    int jbase = jt * 128;
    int lrow = lane & 15, lgrp = lane >> 4;

    float4v acc[8];
#pragma unroll
    for (int i = 0; i < 8; ++i) acc[i] = {0.f, 0.f, 0.f, 0.f};

#pragma unroll
    for (int ms = 0; ms < 4; ++ms) {
        int m0 = ms * 32;
        short8 a = *(const short8*)(Wt + (c0 + lrow) * F_ + m0 + lgrp * 8);
        float4v hv0[8], hv1[8];
#pragma unroll
        for (int cf = 0; cf < 8; ++cf) {
            const float* hp = H + ((size_t)b * N_ + jbase + cf * 16 + lrow) * F_ + m0 + lgrp * 8;
            hv0[cf] = *(const float4v*)hp;
            hv1[cf] = *(const float4v*)(hp + 4);
        }
#pragma unroll
        for (int cf = 0; cf < 8; ++cf) {
            short8 bb = pack8(hv0[cf], hv1[cf]);
            acc[cf] = __builtin_amdgcn_mfma_f32_16x16x32_bf16(a, bb, acc[cf], 0, 0, 0);
        }
    }
#pragma unroll
    for (int cf = 0; cf < 8; ++cf) {
#pragma unroll
        for (int r = 0; r < 4; ++r) {
            int c = c0 + lgrp * 4 + r;
            int j = jbase + cf * 16 + lrow;
            Tt[((size_t)b * 512 + c) * N_ + j] = f2bf(acc[cf][r]);
        }
    }
}

// ---------------- kA: FUSED colsum + rel partials (E read exactly ONCE, f32) ----------
// grid: b(32) x it(8) x jc(4) = 1024 blocks, 512 threads (8 waves: 4 i-sub x 2 f-half).
// iter t (0..15): js = t>>2 (outer), k = t&3 (inner) -> lane's colsum columns fixed
// within each js group of 4 k-iters; flush per js via 16-lane shfl reduce + atomics.
__global__ void __launch_bounds__(512)
kA_fused(const float* __restrict__ E, const unsigned short* __restrict__ Tt,
         float* __restrict__ colsum, float* __restrict__ relP) {
    int bid = blockIdx.x;
    int b  = bid >> 5;
    int it = (bid >> 2) & 7;
    int jc = bid & 3;
    int lane = threadIdx.x & 63;
    int wv   = threadIdx.x >> 6;
    int i0 = it * 64 + (wv >> 1) * 16;
    int f0 = (wv & 1) * 64;
    int lrow = lane & 15, lgrp = lane >> 4;
    int jbase = jc * 128;
    bool do_cs = (wv & 1) == 0;   // f-half 0 waves own colsum (avoid double count)

    float4v acc[4];
#pragma unroll
    for (int i = 0; i < 4; ++i) acc[i] = {0.f, 0.f, 0.f, 0.f};
    float cs[8];
#pragma unroll
    for (int e = 0; e < 8; ++e) cs[e] = 0.f;

    // E f32: k-stride 262144 (=N*N), js-stride 32. Tt bf16: k-stride 65536, cf*16 rows=8192, js 32.
    const float* Eb = E + ((size_t)(b * K_) * N_ + (i0 + lrow)) * N_ + jbase + lgrp * 8;
    const unsigned short* Tb = Tt + ((size_t)b * 512 + f0 + lrow) * N_ + jbase + lgrp * 8;

#define EA0(t) (const float4v*)(Eb + ((t) & 3) * 262144 + ((t) >> 2) * 32)
#define EA1(t) (const float4v*)(Eb + ((t) & 3) * 262144 + ((t) >> 2) * 32 + 4)
#define TA(t, cf) (const short8*)(Tb + ((t) & 3) * 65536 + (cf) * 8192 + ((t) >> 2) * 32)

    float4v ea0, eb0, ea1, eb1;
    short8 t00, t01, t02, t03, t10, t11, t12, t13;
    ea0 = *EA0(0); eb0 = *EA1(0);
    t00 = *TA(0, 0); t01 = *TA(0, 1); t02 = *TA(0, 2); t03 = *TA(0, 3);

#pragma unroll
    for (int t = 0; t < 16; t += 2) {
        int t1 = t + 1;
        int t2 = (t + 2 < 16) ? t + 2 : 15;   // tail duplicate, harmless
        // stage odd iter while consuming even
        ea1 = *EA0(t1); eb1 = *EA1(t1);
        t10 = *TA(t1, 0); t11 = *TA(t1, 1); t12 = *TA(t1, 2); t13 = *TA(t1, 3);
        {
            short8 a = pack8(ea0, eb0);
            acc[0] = __builtin_amdgcn_mfma_f32_16x16x32_bf16(a, t00, acc[0], 0, 0, 0);
            acc[1] = __builtin_amdgcn_mfma_f32_16x16x32_bf16(a, t01, acc[1], 0, 0, 0);
            acc[2] = __builtin_amdgcn_mfma_f32_16x16x32_bf16(a, t02, acc[2], 0, 0, 0);
            acc[3] = __builtin_amdgcn_mfma_f32_16x16x32_bf16(a, t03, acc[3], 0, 0, 0);
            if (do_cs) {
                cs[0] += ea0[0]; cs[1] += ea0[1]; cs[2] += ea0[2]; cs[3] += ea0[3];
                cs[4] += eb0[0]; cs[5] += eb0[1]; cs[6] += eb0[2]; cs[7] += eb0[3];
            }
        }
        // stage next even while consuming odd
        ea0 = *EA0(t2); eb0 = *EA1(t2);
        t00 = *TA(t2, 0); t01 = *TA(t2, 1); t02 = *TA(t2, 2); t03 = *TA(t2, 3);
        {
            short8 a = pack8(ea1, eb1);
            acc[0] = __builtin_amdgcn_mfma_f32_16x16x32_bf16(a, t10, acc[0], 0, 0, 0);
            acc[1] = __builtin_amdgcn_mfma_f32_16x16x32_bf16(a, t11, acc[1], 0, 0, 0);
            acc[2] = __builtin_amdgcn_mfma_f32_16x16x32_bf16(a, t12, acc[2], 0, 0, 0);
            acc[3] = __builtin_amdgcn_mfma_f32_16x16x32_bf16(a, t13, acc[3], 0, 0, 0);
            if (do_cs) {
                cs[0] += ea1[0]; cs[1] += ea1[1]; cs[2] += ea1[2]; cs[3] += ea1[3];
                cs[4] += eb1[0]; cs[5] += eb1[1]; cs[6] += eb1[2]; cs[7] += eb1[3];
            }
        }
        if (((t1) & 3) == 3) {
            // js group complete (4 k-iters consumed): reduce over 16 lrow-lanes, flush.
            int js = t1 >> 2;
            if (do_cs) {
#pragma unroll
                for (int e = 0; e < 8; ++e) {
                    cs[e] += __shfl_xor(cs[e], 1);
                    cs[e] += __shfl_xor(cs[e], 2);
                    cs[e] += __shfl_xor(cs[e], 4);
                    cs[e] += __shfl_xor(cs[e], 8);
                }
                if (lrow == 0) {
#pragma unroll
                    for (int e = 0; e < 8; ++e)
                        atomicAdd(&colsum[b * N_ + jbase + js * 32 + lgrp * 8 + e], cs[e]);
                }
#pragma unroll
                for (int e = 0; e < 8; ++e) cs[e] = 0.f;
            }
        }
    }
#undef EA0
#undef EA1
#undef TA

    float* dst = relP + (size_t)jc * (B_ * N_ * F_);
#pragma unroll
    for (int cf = 0; cf < 4; ++cf) {
#pragma unroll
        for (int r = 0; r < 4; ++r) {
            int i = i0 + lgrp * 4 + r;
            int f = f0 + cf * 16 + lrow;
            dst[((size_t)b * N_ + i) * F_ + f] = acc[cf][r];
        }
    }
}

// ---------------- k4: epilogue — self-term MFMA + D*(sum of 4 rel partials) + sigmoid --
__global__ void __launch_bounds__(512)
k4_epi(const float* __restrict__ relP, const float* __restrict__ H,
       const unsigned short* __restrict__ SWt, const float* __restrict__ colsum,
       float* __restrict__ out) {
    int bid = blockIdx.x;
    int b  = bid >> 3;
    int it = bid & 7;
    int lane = threadIdx.x & 63;
    int wv   = threadIdx.x >> 6;
    int i0 = it * 64 + (wv >> 1) * 16;
    int f0 = (wv & 1) * 64;
    int lrow = lane & 15, lgrp = lane >> 4;

    float4v accS[4];
#pragma unroll
    for (int i = 0; i < 4; ++i) accS[i] = {0.f, 0.f, 0.f, 0.f};

    const float* Hp = H + ((size_t)b * N_ + i0 + lrow) * F_;
#pragma unroll
    for (int ms = 0; ms < 4; ++ms) {
        int m0 = ms * 32;
        const float* hp = Hp + m0 + lgrp * 8;
        float4v h0 = *(const float4v*)hp;
        float4v h1 = *(const float4v*)(hp + 4);
        short8 a = pack8(h0, h1);
#pragma unroll
        for (int cf = 0; cf < 4; ++cf) {
            const unsigned short* sp = SWt + (f0 + cf * 16 + lrow) * F_ + m0 + lgrp * 8;
            short8 bb = *(const short8*)sp;
            accS[cf] = __builtin_amdgcn_mfma_f32_16x16x32_bf16(a, bb, accS[cf], 0, 0, 0);
        }
    }

    float Dv[4];
#pragma unroll
    for (int r = 0; r < 4; ++r) {
        int i = i0 + lgrp * 4 + r;
        Dv[r] = 1.0f / (colsum[b * N_ + i] + (float)K_);
    }
    const size_t S = (size_t)B_ * N_ * F_;
#pragma unroll
    for (int cf = 0; cf < 4; ++cf) {
#pragma unroll
        for (int r = 0; r < 4; ++r) {
            int i = i0 + lgrp * 4 + r;
            int f = f0 + cf * 16 + lrow;
            size_t idx = ((size_t)b * N_ + i) * F_ + f;
            float v = relP[idx] + relP[idx + S] + relP[idx + 2 * S] + relP[idx + 3 * S];
            float x = Dv[r] * v + accS[cf][r];
            out[idx] = 1.0f / (1.0f + __expf(-x));
        }
    }
}

// ================= fallback (validated round-5 kernels) =================
__global__ void k1_colsum(const float* __restrict__ E, float* __restrict__ colsum) {
    int bid = blockIdx.x;
    int b   = bid >> 5;
    int jt  = (bid >> 4) & 1;
    int isl = bid & 15;
    int j   = jt * 256 + threadIdx.x;
    int i0  = isl * 32;
    float s0 = 0.f, s1 = 0.f, s2 = 0.f, s3 = 0.f;
#pragma unroll
    for (int k = 0; k < K_; ++k) {
        const float* p = E + ((size_t)((b * K_ + k) * N_ + i0)) * N_ + j;
#pragma unroll 4
        for (int ii = 0; ii < 32; ii += 4) {
            s0 += p[(ii + 0) * N_];
            s1 += p[(ii + 1) * N_];
            s2 += p[(ii + 2) * N_];
            s3 += p[(ii + 3) * N_];
        }
    }
    atomicAdd(&colsum[b * N_ + j], (s0 + s1) + (s2 + s3));
}

__global__ void __launch_bounds__(512)
k3_fuse(const float* __restrict__ E, const float* __restrict__ H,
        const unsigned short* __restrict__ Tt, const unsigned short* __restrict__ SWt,
        const float* __restrict__ colsum, float* __restrict__ out) {
    int bid = blockIdx.x;
    int b  = bid >> 3;
    int it = bid & 7;
    int lane = threadIdx.x & 63;
    int wv   = threadIdx.x >> 6;
    int i0 = it * 64 + (wv >> 1) * 16;
    int f0 = (wv & 1) * 64;
    int lrow = lane & 15, lgrp = lane >> 4;

    float4v accR[4], accS[4];
#pragma unroll
    for (int i = 0; i < 4; ++i) { accR[i] = {0.f, 0.f, 0.f, 0.f}; accS[i] = {0.f, 0.f, 0.f, 0.f}; }

    for (int k = 0; k < K_; ++k) {
        const float* Eb = E + ((size_t)((b * K_ + k) * N_ + i0 + lrow)) * N_;
        const unsigned short* Tb = Tt + ((size_t)b * 512 + k * 128 + f0) * N_;
#pragma unroll 2
        for (int js = 0; js < 16; ++js) {
            int j0 = js * 32;
            const float* ep = Eb + j0 + lgrp * 8;
            float4v e0 = *(const float4v*)ep;
            float4v e1 = *(const float4v*)(ep + 4);
            short8 a = pack8(e0, e1);
#pragma unroll
            for (int cf = 0; cf < 4; ++cf) {
                const unsigned short* tp = Tb + (size_t)(cf * 16 + lrow) * N_ + j0 + lgrp * 8;
                short8 bb = *(const short8*)tp;
                accR[cf] = __builtin_amdgcn_mfma_f32_16x16x32_bf16(a, bb, accR[cf], 0, 0, 0);
            }
        }
    }
    {
        const float* Hp = H + ((size_t)b * N_ + i0 + lrow) * F_;
#pragma unroll
        for (int ms = 0; ms < 4; ++ms) {
            int m0 = ms * 32;
            const float* hp = Hp + m0 + lgrp * 8;
            float4v h0 = *(const float4v*)hp;
            float4v h1 = *(const float4v*)(hp + 4);
            short8 a = pack8(h0, h1);
#pragma unroll
            for (int cf = 0; cf < 4; ++cf) {
                const unsigned short* sp = SWt + (f0 + cf * 16 + lrow) * F_ + m0 + lgrp * 8;
                short8 bb = *(const short8*)sp;
                accS[cf] = __builtin_amdgcn_mfma_f32_16x16x32_bf16(a, bb, accS[cf], 0, 0, 0);
            }
        }
    }
    float Dv[4];
#pragma unroll
    for (int r = 0; r < 4; ++r) {
        int i = i0 + lgrp * 4 + r;
        Dv[r] = 1.0f / (colsum[b * N_ + i] + (float)K_);
    }
#pragma unroll
    for (int cf = 0; cf < 4; ++cf) {
#pragma unroll
        for (int r = 0; r < 4; ++r) {
            int i = i0 + lgrp * 4 + r;
            int f = f0 + cf * 16 + lrow;
            float x = Dv[r] * accR[cf][r] + accS[cf][r];
            out[((size_t)b * N_ + i) * F_ + f] = 1.0f / (1.0f + __expf(-x));
        }
    }
}

extern "C" void kernel_launch(void* const* d_in, const int* in_sizes, int n_in,
                              void* d_out, int out_size, void* d_ws, size_t ws_size,
                              hipStream_t stream) {
    const float* H  = (const float*)d_in[0];
    const float* E  = (const float*)d_in[1];
    const float* RW = (const float*)d_in[2];
    const float* SW = (const float*)d_in[3];
    float* out = (float*)d_out;

    char* ws = (char*)d_ws;
    unsigned short* Wt  = (unsigned short*)(ws);               // 128 KiB
    unsigned short* SWt = (unsigned short*)(ws + 131072);      //  32 KiB
    float* colsum       = (float*)(ws + 163840);               //  64 KiB
    unsigned short* Tt  = (unsigned short*)(ws + 262144);      //  16 MiB
    float* relP         = (float*)(ws + 17039360);             //  32 MiB (4 x 8 MiB)
    const size_t WS_NEED = 50593792ull;

    hipMemsetAsync(colsum, 0, B_ * N_ * sizeof(float), stream);
    k0_weights<<<640, 128, 0, stream>>>(RW, SW, Wt, SWt);
    k2v2_expand<<<1024, 256, 0, stream>>>(H, Wt, Tt);

    if (ws_size >= WS_NEED) {
        kA_fused<<<1024, 512, 0, stream>>>(E, Tt, colsum, relP);
        k4_epi<<<256, 512, 0, stream>>>(relP, H, SWt, colsum, out);
    } else {
        k1_colsum<<<1024, 256, 0, stream>>>(E, colsum);
        k3_fuse<<<256, 512, 0, stream>>>(E, H, Tt, SWt, colsum, out);
    }
}

// Round 12
// 283.427 us; speedup vs baseline: 1.2072x; 1.1515x over previous
//
#include <hip/hip_runtime.h>
#include <hip/hip_bf16.h>

#define B_ 32
#define K_ 4
#define N_ 512
#define F_ 128

typedef __attribute__((ext_vector_type(8))) short short8;
typedef __attribute__((ext_vector_type(4))) float float4v;

__device__ __forceinline__ unsigned short f2bf(float x) {
    unsigned int u = __builtin_bit_cast(unsigned int, x);
    u += 0x7FFFu + ((u >> 16) & 1u);
    return (unsigned short)(u >> 16);
}

__device__ __forceinline__ short8 pack8(float4v a, float4v b) {
    short8 r;
    r[0] = (short)f2bf(a[0]); r[1] = (short)f2bf(a[1]);
    r[2] = (short)f2bf(a[2]); r[3] = (short)f2bf(a[3]);
    r[4] = (short)f2bf(b[0]); r[5] = (short)f2bf(b[1]);
    r[6] = (short)f2bf(b[2]); r[7] = (short)f2bf(b[3]);
    return r;
}

__device__ __forceinline__ void gl16(const void* g, void* l) {
    __builtin_amdgcn_global_load_lds(
        (const __attribute__((address_space(1))) void*)g,
        (__attribute__((address_space(3))) void*)l, 16, 0, 0);
}

// ---------------- k0: weight transposes (tiny) ----------------
__global__ void k0_weights(const float* __restrict__ RW, const float* __restrict__ SW,
                           unsigned short* __restrict__ Wt, unsigned short* __restrict__ SWt) {
    int r = blockIdx.x;   // 0..639
    int m = threadIdx.x;  // 0..127
    if (r < 512) {
        int k = r >> 7, f = r & 127;
        Wt[r * F_ + m] = f2bf(RW[(m * F_ + f) * K_ + k]);
    } else {
        int l = r - 512;
        SWt[l * F_ + m] = f2bf(SW[m * F_ + l]);
    }
}

// ---------------- kS: streaming E->bf16 + colsum (shallow threads, fillBuffer-like) ----
// grid: b(32) x k(4) x rslab(16) x cslab(8) = 16384 blocks, 256 thr.
// thread t: row = rslab*32 + (t>>3), cols = cslab*64 + (t&7)*8 (2 indep float4 loads).
__global__ void __launch_bounds__(256)
kS_stream(const float* __restrict__ E, float* __restrict__ colsum,
          unsigned short* __restrict__ Ebf) {
    int bid = blockIdx.x;
    int b     = bid >> 9;
    int k     = (bid >> 7) & 3;
    int rslab = (bid >> 3) & 15;
    int cslab = bid & 7;
    int t = threadIdx.x;
    int rl = t >> 3;            // 0..31
    int cl = (t & 7) * 8;       // 0..56

    size_t base = ((size_t)((b * K_ + k) * N_ + rslab * 32 + rl)) * N_ + cslab * 64 + cl;
    float4v v0 = *(const float4v*)(E + base);
    float4v v1 = *(const float4v*)(E + base + 4);
    *(short8*)(Ebf + base) = pack8(v0, v1);

    __shared__ float red[32][65];
    red[rl][cl + 0] = v0[0]; red[rl][cl + 1] = v0[1];
    red[rl][cl + 2] = v0[2]; red[rl][cl + 3] = v0[3];
    red[rl][cl + 4] = v1[0]; red[rl][cl + 5] = v1[1];
    red[rl][cl + 6] = v1[2]; red[rl][cl + 7] = v1[3];
    __syncthreads();
    if (t < 64) {
        float s = 0.f;
#pragma unroll
        for (int r = 0; r < 32; ++r) s += red[r][t];
        atomicAdd(&colsum[b * N_ + cslab * 64 + t], s);
    }
}

// ---------------- k2v2: Tt[b][c][j] = sum_m Wt[c][m]*H[b][j][m] (validated r9) --------
__global__ void __launch_bounds__(256)
k2v2_expand(const float* __restrict__ H, const unsigned short* __restrict__ Wt,
            unsigned short* __restrict__ Tt) {
    int bid = blockIdx.x;        // 1024 blocks
    int b  = bid >> 5;
    int ct = (bid >> 2) & 7;
    int jt = bid & 3;
    int lane = threadIdx.x & 63;
    int wv   = threadIdx.x >> 6;
    int c0 = ct * 64 + wv * 16;
    int jbase = jt * 128;
    int lrow = lane & 15, lgrp = lane >> 4;

    float4v acc[8];
#pragma unroll
    for (int i = 0; i < 8; ++i) acc[i] = {0.f, 0.f, 0.f, 0.f};

#pragma unroll
    for (int ms = 0; ms < 4; ++ms) {
        int m0 = ms * 32;
        short8 a = *(const short8*)(Wt + (c0 + lrow) * F_ + m0 + lgrp * 8);
        float4v hv0[8], hv1[8];
#pragma unroll
        for (int cf = 0; cf < 8; ++cf) {
            const float* hp = H + ((size_t)b * N_ + jbase + cf * 16 + lrow) * F_ + m0 + lgrp * 8;
            hv0[cf] = *(const float4v*)hp;
            hv1[cf] = *(const float4v*)(hp + 4);
        }
#pragma unroll
        for (int cf = 0; cf < 8; ++cf) {
            short8 bb = pack8(hv0[cf], hv1[cf]);
            acc[cf] = __builtin_amdgcn_mfma_f32_16x16x32_bf16(a, bb, acc[cf], 0, 0, 0);
        }
    }
#pragma unroll
    for (int cf = 0; cf < 8; ++cf) {
#pragma unroll
        for (int r = 0; r < 4; ++r) {
            int c = c0 + lgrp * 4 + r;
            int j = jbase + cf * 16 + lrow;
            Tt[((size_t)b * 512 + c) * N_ + j] = f2bf(acc[cf][r]);
        }
    }
}

// ---------------- kB: rel via global_load_lds double-buffered pipeline ----------------
// grid: b(32) x it(8) x jc(2) = 512 blocks, 512 thr (8 waves = 4 isub x 2 fhalf).
// 32 steps (js 0..7 x k 0..3): stage E-tile[64i x 32j] + T-tile[128f x 32j] bf16 in LDS,
// XOR-swizzled (granule g ^= r&3) on BOTH source and read (rule #21).
__global__ void __launch_bounds__(512)
kB_rel(const unsigned short* __restrict__ Ebf, const unsigned short* __restrict__ Tt,
       float* __restrict__ relP) {
    __shared__ char smem[24576];   // 2 x (4 KiB E + 8 KiB T)
    int bid = blockIdx.x;
    int b  = bid >> 4;
    int it = (bid >> 1) & 7;
    int jc = bid & 1;
    int tid = threadIdx.x;
    int lane = tid & 63, wv = tid >> 6;
    int lrow = lane & 15, lgrp = lane >> 4;
    int isub = wv >> 1, fh = wv & 1;

    float4v acc[4];
#pragma unroll
    for (int i = 0; i < 4; ++i) acc[i] = {0.f, 0.f, 0.f, 0.f};

    // per-wave stage slots (r = tile row, g = 16B granule; source pre-inverse-swizzled)
    int slotT = wv * 64 + lane;            // 0..511 -> T rows 0..127
    int rT = slotT >> 2, gT = slotT & 3;
    int colT = (gT ^ (rT & 3)) * 8;
    int slotE = (wv & 3) * 64 + lane;      // waves 0-3 -> E rows 0..63
    int rE = slotE >> 2, gE = slotE & 3;
    int colE = (gE ^ (rE & 3)) * 8;

    const unsigned short* Tbase = Tt + ((size_t)(b * 512 + rT)) * N_ + jc * 256 + colT;
    const unsigned short* Ebase = Ebf + ((size_t)(b * K_ * N_) + it * 64 + rE) * N_ + jc * 256 + colE;

#define STAGE(bufoff, kk, js)                                                        \
    {                                                                                \
        gl16(Tbase + (size_t)(kk) * (128 * N_) + (js) * 32,                          \
             smem + (bufoff) + 4096 + wv * 1024);                                    \
        if (wv < 4)                                                                  \
            gl16(Ebase + (size_t)(kk) * (N_ * N_) + (js) * 32,                       \
                 smem + (bufoff) + (wv & 3) * 1024);                                 \
    }

    // step t: k = t&3, js = t>>2
    STAGE(0, 0, 0);
    __syncthreads();

    int rA = isub * 16 + lrow;
    int eoffA = rA * 64 + ((lgrp ^ (rA & 3)) << 4);
    int toff0 = (fh * 64 + 0 * 16 + lrow) * 64 + ((lgrp ^ (lrow & 3)) << 4);
    int toff1 = (fh * 64 + 1 * 16 + lrow) * 64 + ((lgrp ^ (lrow & 3)) << 4);
    int toff2 = (fh * 64 + 2 * 16 + lrow) * 64 + ((lgrp ^ (lrow & 3)) << 4);
    int toff3 = (fh * 64 + 3 * 16 + lrow) * 64 + ((lgrp ^ (lrow & 3)) << 4);

    int cur = 0;
    for (int t = 0; t < 32; ++t) {
        int nxt = cur ^ 12288;
        if (t + 1 < 32) {
            int k1 = (t + 1) & 3, js1 = (t + 1) >> 2;
            STAGE(nxt, k1, js1);
        }
        short8 a  = *(const short8*)(smem + cur + eoffA);
        short8 b0 = *(const short8*)(smem + cur + 4096 + toff0);
        short8 b1 = *(const short8*)(smem + cur + 4096 + toff1);
        short8 b2 = *(const short8*)(smem + cur + 4096 + toff2);
        short8 b3 = *(const short8*)(smem + cur + 4096 + toff3);
        acc[0] = __builtin_amdgcn_mfma_f32_16x16x32_bf16(a, b0, acc[0], 0, 0, 0);
        acc[1] = __builtin_amdgcn_mfma_f32_16x16x32_bf16(a, b1, acc[1], 0, 0, 0);
        acc[2] = __builtin_amdgcn_mfma_f32_16x16x32_bf16(a, b2, acc[2], 0, 0, 0);
        acc[3] = __builtin_amdgcn_mfma_f32_16x16x32_bf16(a, b3, acc[3], 0, 0, 0);
        __syncthreads();
        cur = nxt;
    }
#undef STAGE

    float* dst = relP + (size_t)jc * (B_ * N_ * F_);
#pragma unroll
    for (int cf = 0; cf < 4; ++cf) {
#pragma unroll
        for (int r = 0; r < 4; ++r) {
            int i = it * 64 + isub * 16 + lgrp * 4 + r;
            int f = fh * 64 + cf * 16 + lrow;
            dst[((size_t)b * N_ + i) * F_ + f] = acc[cf][r];
        }
    }
}

// ---------------- k4: epilogue (r5-validated, 2 partials) ----------------
__global__ void __launch_bounds__(512)
k4_epi2(const float* __restrict__ relP, const float* __restrict__ H,
        const unsigned short* __restrict__ SWt, const float* __restrict__ colsum,
        float* __restrict__ out) {
    int bid = blockIdx.x;
    int b  = bid >> 3;
    int it = bid & 7;
    int lane = threadIdx.x & 63;
    int wv   = threadIdx.x >> 6;
    int i0 = it * 64 + (wv >> 1) * 16;
    int f0 = (wv & 1) * 64;
    int lrow = lane & 15, lgrp = lane >> 4;

    float4v accS[4];
#pragma unroll
    for (int i = 0; i < 4; ++i) accS[i] = {0.f, 0.f, 0.f, 0.f};

    const float* Hp = H + ((size_t)b * N_ + i0 + lrow) * F_;
#pragma unroll
    for (int ms = 0; ms < 4; ++ms) {
        int m0 = ms * 32;
        const float* hp = Hp + m0 + lgrp * 8;
        float4v h0 = *(const float4v*)hp;
        float4v h1 = *(const float4v*)(hp + 4);
        short8 a = pack8(h0, h1);
#pragma unroll
        for (int cf = 0; cf < 4; ++cf) {
            const unsigned short* sp = SWt + (f0 + cf * 16 + lrow) * F_ + m0 + lgrp * 8;
            short8 bb = *(const short8*)sp;
            accS[cf] = __builtin_amdgcn_mfma_f32_16x16x32_bf16(a, bb, accS[cf], 0, 0, 0);
        }
    }

    float Dv[4];
#pragma unroll
    for (int r = 0; r < 4; ++r) {
        int i = i0 + lgrp * 4 + r;
        Dv[r] = 1.0f / (colsum[b * N_ + i] + (float)K_);
    }
    const size_t S = (size_t)B_ * N_ * F_;
#pragma unroll
    for (int cf = 0; cf < 4; ++cf) {
#pragma unroll
        for (int r = 0; r < 4; ++r) {
            int i = i0 + lgrp * 4 + r;
            int f = f0 + cf * 16 + lrow;
            size_t idx = ((size_t)b * N_ + i) * F_ + f;
            float v = relP[idx] + relP[idx + S];
            float x = Dv[r] * v + accS[cf][r];
            out[idx] = 1.0f / (1.0f + __expf(-x));
        }
    }
}

// ================= fallback (validated round-5 kernels) =================
__global__ void k1_colsum(const float* __restrict__ E, float* __restrict__ colsum) {
    int bid = blockIdx.x;
    int b   = bid >> 5;
    int jt  = (bid >> 4) & 1;
    int isl = bid & 15;
    int j   = jt * 256 + threadIdx.x;
    int i0  = isl * 32;
    float s0 = 0.f, s1 = 0.f, s2 = 0.f, s3 = 0.f;
#pragma unroll
    for (int k = 0; k < K_; ++k) {
        const float* p = E + ((size_t)((b * K_ + k) * N_ + i0)) * N_ + j;
#pragma unroll 4
        for (int ii = 0; ii < 32; ii += 4) {
            s0 += p[(ii + 0) * N_];
            s1 += p[(ii + 1) * N_];
            s2 += p[(ii + 2) * N_];
            s3 += p[(ii + 3) * N_];
        }
    }
    atomicAdd(&colsum[b * N_ + j], (s0 + s1) + (s2 + s3));
}

__global__ void __launch_bounds__(512)
k3_fuse(const float* __restrict__ E, const float* __restrict__ H,
        const unsigned short* __restrict__ Tt, const unsigned short* __restrict__ SWt,
        const float* __restrict__ colsum, float* __restrict__ out) {
    int bid = blockIdx.x;
    int b  = bid >> 3;
    int it = bid & 7;
    int lane = threadIdx.x & 63;
    int wv   = threadIdx.x >> 6;
    int i0 = it * 64 + (wv >> 1) * 16;
    int f0 = (wv & 1) * 64;
    int lrow = lane & 15, lgrp = lane >> 4;

    float4v accR[4], accS[4];
#pragma unroll
    for (int i = 0; i < 4; ++i) { accR[i] = {0.f, 0.f, 0.f, 0.f}; accS[i] = {0.f, 0.f, 0.f, 0.f}; }

    for (int k = 0; k < K_; ++k) {
        const float* Eb = E + ((size_t)((b * K_ + k) * N_ + i0 + lrow)) * N_;
        const unsigned short* Tb = Tt + ((size_t)b * 512 + k * 128 + f0) * N_;
#pragma unroll 2
        for (int js = 0; js < 16; ++js) {
            int j0 = js * 32;
            const float* ep = Eb + j0 + lgrp * 8;
            float4v e0 = *(const float4v*)ep;
            float4v e1 = *(const float4v*)(ep + 4);
            short8 a = pack8(e0, e1);
#pragma unroll
            for (int cf = 0; cf < 4; ++cf) {
                const unsigned short* tp = Tb + (size_t)(cf * 16 + lrow) * N_ + j0 + lgrp * 8;
                short8 bb = *(const short8*)tp;
                accR[cf] = __builtin_amdgcn_mfma_f32_16x16x32_bf16(a, bb, accR[cf], 0, 0, 0);
            }
        }
    }
    {
        const float* Hp = H + ((size_t)b * N_ + i0 + lrow) * F_;
#pragma unroll
        for (int ms = 0; ms < 4; ++ms) {
            int m0 = ms * 32;
            const float* hp = Hp + m0 + lgrp * 8;
            float4v h0 = *(const float4v*)hp;
            float4v h1 = *(const float4v*)(hp + 4);
            short8 a = pack8(h0, h1);
#pragma unroll
            for (int cf = 0; cf < 4; ++cf) {
                const unsigned short* sp = SWt + (f0 + cf * 16 + lrow) * F_ + m0 + lgrp * 8;
                short8 bb = *(const short8*)sp;
                accS[cf] = __builtin_amdgcn_mfma_f32_16x16x32_bf16(a, bb, accS[cf], 0, 0, 0);
            }
        }
    }
    float Dv[4];
#pragma unroll
    for (int r = 0; r < 4; ++r) {
        int i = i0 + lgrp * 4 + r;
        Dv[r] = 1.0f / (colsum[b * N_ + i] + (float)K_);
    }
#pragma unroll
    for (int cf = 0; cf < 4; ++cf) {
#pragma unroll
        for (int r = 0; r < 4; ++r) {
            int i = i0 + lgrp * 4 + r;
            int f = f0 + cf * 16 + lrow;
            float x = Dv[r] * accR[cf][r] + accS[cf][r];
            out[((size_t)b * N_ + i) * F_ + f] = 1.0f / (1.0f + __expf(-x));
        }
    }
}

extern "C" void kernel_launch(void* const* d_in, const int* in_sizes, int n_in,
                              void* d_out, int out_size, void* d_ws, size_t ws_size,
                              hipStream_t stream) {
    const float* H  = (const float*)d_in[0];
    const float* E  = (const float*)d_in[1];
    const float* RW = (const float*)d_in[2];
    const float* SW = (const float*)d_in[3];
    float* out = (float*)d_out;

    char* ws = (char*)d_ws;
    unsigned short* Wt  = (unsigned short*)(ws);               // 128 KiB
    unsigned short* SWt = (unsigned short*)(ws + 131072);      //  32 KiB
    float* colsum       = (float*)(ws + 163840);               //  64 KiB
    unsigned short* Tt  = (unsigned short*)(ws + 262144);      //  16 MiB
    unsigned short* Ebf = (unsigned short*)(ws + 17039360);    //  64 MiB
    float* relP         = (float*)(ws + 84148224);             //  16 MiB (2 x 8 MiB)
    const size_t WS_NEED = 100925440ull;   // proven available (r7 ran this path)

    hipMemsetAsync(colsum, 0, B_ * N_ * sizeof(float), stream);
    k0_weights<<<640, 128, 0, stream>>>(RW, SW, Wt, SWt);

    if (ws_size >= WS_NEED) {
        kS_stream<<<16384, 256, 0, stream>>>(E, colsum, Ebf);
        k2v2_expand<<<1024, 256, 0, stream>>>(H, Wt, Tt);
        kB_rel<<<512, 512, 0, stream>>>(Ebf, Tt, relP);
        k4_epi2<<<256, 512, 0, stream>>>(relP, H, SWt, colsum, out);
    } else {
        k1_colsum<<<1024, 256, 0, stream>>>(E, colsum);
        k2v2_expand<<<1024, 256, 0, stream>>>(H, Wt, Tt);
        k3_fuse<<<256, 512, 0, stream>>>(E, H, Tt, SWt, colsum, out);
    }
}

// Round 13
// 283.203 us; speedup vs baseline: 1.2082x; 1.0008x over previous
//
#include <hip/hip_runtime.h>
#include <hip/hip_bf16.h>

#define B_ 32
#define K_ 4
#define N_ 512
#define F_ 128

typedef __attribute__((ext_vector_type(8))) short short8;
typedef __attribute__((ext_vector_type(4))) float float4v;

__device__ __forceinline__ unsigned short f2bf(float x) {
    unsigned int u = __builtin_bit_cast(unsigned int, x);
    u += 0x7FFFu + ((u >> 16) & 1u);
    return (unsigned short)(u >> 16);
}

__device__ __forceinline__ short8 pack8(float4v a, float4v b) {
    short8 r;
    r[0] = (short)f2bf(a[0]); r[1] = (short)f2bf(a[1]);
    r[2] = (short)f2bf(a[2]); r[3] = (short)f2bf(a[3]);
    r[4] = (short)f2bf(b[0]); r[5] = (short)f2bf(b[1]);
    r[6] = (short)f2bf(b[2]); r[7] = (short)f2bf(b[3]);
    return r;
}

__device__ __forceinline__ void gl16(const void* g, void* l) {
    __builtin_amdgcn_global_load_lds(
        (const __attribute__((address_space(1))) void*)g,
        (__attribute__((address_space(3))) void*)l, 16, 0, 0);
}

// ---------------- k0: weight transposes (tiny) ----------------
__global__ void k0_weights(const float* __restrict__ RW, const float* __restrict__ SW,
                           unsigned short* __restrict__ Wt, unsigned short* __restrict__ SWt) {
    int r = blockIdx.x;   // 0..639
    int m = threadIdx.x;  // 0..127
    if (r < 512) {
        int k = r >> 7, f = r & 127;
        Wt[r * F_ + m] = f2bf(RW[(m * F_ + f) * K_ + k]);
    } else {
        int l = r - 512;
        SWt[l * F_ + m] = f2bf(SW[m * F_ + l]);
    }
}

// ---------------- kS: streaming E->bf16 + colsum (r12-validated) ----------------
__global__ void __launch_bounds__(256)
kS_stream(const float* __restrict__ E, float* __restrict__ colsum,
          unsigned short* __restrict__ Ebf) {
    int bid = blockIdx.x;
    int b     = bid >> 9;
    int k     = (bid >> 7) & 3;
    int rslab = (bid >> 3) & 15;
    int cslab = bid & 7;
    int t = threadIdx.x;
    int rl = t >> 3;            // 0..31
    int cl = (t & 7) * 8;       // 0..56

    size_t base = ((size_t)((b * K_ + k) * N_ + rslab * 32 + rl)) * N_ + cslab * 64 + cl;
    float4v v0 = *(const float4v*)(E + base);
    float4v v1 = *(const float4v*)(E + base + 4);
    *(short8*)(Ebf + base) = pack8(v0, v1);

    __shared__ float red[32][65];
    red[rl][cl + 0] = v0[0]; red[rl][cl + 1] = v0[1];
    red[rl][cl + 2] = v0[2]; red[rl][cl + 3] = v0[3];
    red[rl][cl + 4] = v1[0]; red[rl][cl + 5] = v1[1];
    red[rl][cl + 6] = v1[2]; red[rl][cl + 7] = v1[3];
    __syncthreads();
    if (t < 64) {
        float s = 0.f;
#pragma unroll
        for (int r = 0; r < 32; ++r) s += red[r][t];
        atomicAdd(&colsum[b * N_ + cslab * 64 + t], s);
    }
}

// ---------------- k2v3: Tt = W x H, LDS-transposed VECTORIZED store ----------------
// Same math/grid as k2v2; only the store path changes: acc -> LDS tile -> short8 stores.
__global__ void __launch_bounds__(256)
k2v3_expand(const float* __restrict__ H, const unsigned short* __restrict__ Wt,
            unsigned short* __restrict__ Tt) {
    __shared__ unsigned short Tl[64][144];   // 288B rows: 16B-aligned, 8-bank shift
    int bid = blockIdx.x;        // 1024 blocks
    int b  = bid >> 5;
    int ct = (bid >> 2) & 7;
    int jt = bid & 3;
    int tid = threadIdx.x;
    int lane = tid & 63;
    int wv   = tid >> 6;
    int c0 = ct * 64 + wv * 16;
    int jbase = jt * 128;
    int lrow = lane & 15, lgrp = lane >> 4;

    float4v acc[8];
#pragma unroll
    for (int i = 0; i < 8; ++i) acc[i] = {0.f, 0.f, 0.f, 0.f};

#pragma unroll
    for (int ms = 0; ms < 4; ++ms) {
        int m0 = ms * 32;
        short8 a = *(const short8*)(Wt + (c0 + lrow) * F_ + m0 + lgrp * 8);
        float4v hv0[8], hv1[8];
#pragma unroll
        for (int cf = 0; cf < 8; ++cf) {
            const float* hp = H + ((size_t)b * N_ + jbase + cf * 16 + lrow) * F_ + m0 + lgrp * 8;
            hv0[cf] = *(const float4v*)hp;
            hv1[cf] = *(const float4v*)(hp + 4);
        }
#pragma unroll
        for (int cf = 0; cf < 8; ++cf) {
            short8 bb = pack8(hv0[cf], hv1[cf]);
            acc[cf] = __builtin_amdgcn_mfma_f32_16x16x32_bf16(a, bb, acc[cf], 0, 0, 0);
        }
    }
    // acc -> LDS (scalar writes, cheap); c_local = wv*16 + lgrp*4 + r, j_local = cf*16 + lrow
#pragma unroll
    for (int cf = 0; cf < 8; ++cf) {
#pragma unroll
        for (int r = 0; r < 4; ++r) {
            Tl[wv * 16 + lgrp * 4 + r][cf * 16 + lrow] = f2bf(acc[cf][r]);
        }
    }
    __syncthreads();
    // cooperative vectorized store: 1024 chunks of 8 shorts; consecutive tid -> consecutive 16B
#pragma unroll
    for (int cch = 0; cch < 4; ++cch) {
        int chunk = cch * 256 + tid;
        int row = chunk >> 4;          // 0..63
        int col8 = chunk & 15;         // 0..15
        short8 v = *(const short8*)(&Tl[row][col8 * 8]);
        *(short8*)(Tt + ((size_t)(b * 512 + ct * 64 + row)) * N_ + jbase + col8 * 8) = v;
    }
}

// ---------------- kB: rel via global_load_lds double-buffered pipeline (r12-validated) --
__global__ void __launch_bounds__(512)
kB_rel(const unsigned short* __restrict__ Ebf, const unsigned short* __restrict__ Tt,
       float* __restrict__ relP) {
    __shared__ char smem[24576];   // 2 x (4 KiB E + 8 KiB T)
    int bid = blockIdx.x;
    int b  = bid >> 4;
    int it = (bid >> 1) & 7;
    int jc = bid & 1;
    int tid = threadIdx.x;
    int lane = tid & 63, wv = tid >> 6;
    int lrow = lane & 15, lgrp = lane >> 4;
    int isub = wv >> 1, fh = wv & 1;

    float4v acc[4];
#pragma unroll
    for (int i = 0; i < 4; ++i) acc[i] = {0.f, 0.f, 0.f, 0.f};

    int slotT = wv * 64 + lane;
    int rT = slotT >> 2, gT = slotT & 3;
    int colT = (gT ^ (rT & 3)) * 8;
    int slotE = (wv & 3) * 64 + lane;
    int rE = slotE >> 2, gE = slotE & 3;
    int colE = (gE ^ (rE & 3)) * 8;

    const unsigned short* Tbase = Tt + ((size_t)(b * 512 + rT)) * N_ + jc * 256 + colT;
    const unsigned short* Ebase = Ebf + ((size_t)(b * K_ * N_) + it * 64 + rE) * N_ + jc * 256 + colE;

#define STAGE(bufoff, kk, js)                                                        \
    {                                                                                \
        gl16(Tbase + (size_t)(kk) * (128 * N_) + (js) * 32,                          \
             smem + (bufoff) + 4096 + wv * 1024);                                    \
        if (wv < 4)                                                                  \
            gl16(Ebase + (size_t)(kk) * (N_ * N_) + (js) * 32,                       \
                 smem + (bufoff) + (wv & 3) * 1024);                                 \
    }

    STAGE(0, 0, 0);
    __syncthreads();

    int rA = isub * 16 + lrow;
    int eoffA = rA * 64 + ((lgrp ^ (rA & 3)) << 4);
    int toff0 = (fh * 64 + 0 * 16 + lrow) * 64 + ((lgrp ^ (lrow & 3)) << 4);
    int toff1 = (fh * 64 + 1 * 16 + lrow) * 64 + ((lgrp ^ (lrow & 3)) << 4);
    int toff2 = (fh * 64 + 2 * 16 + lrow) * 64 + ((lgrp ^ (lrow & 3)) << 4);
    int toff3 = (fh * 64 + 3 * 16 + lrow) * 64 + ((lgrp ^ (lrow & 3)) << 4);

    int cur = 0;
    for (int t = 0; t < 32; ++t) {
        int nxt = cur ^ 12288;
        if (t + 1 < 32) {
            int k1 = (t + 1) & 3, js1 = (t + 1) >> 2;
            STAGE(nxt, k1, js1);
        }
        short8 a  = *(const short8*)(smem + cur + eoffA);
        short8 b0 = *(const short8*)(smem + cur + 4096 + toff0);
        short8 b1 = *(const short8*)(smem + cur + 4096 + toff1);
        short8 b2 = *(const short8*)(smem + cur + 4096 + toff2);
        short8 b3 = *(const short8*)(smem + cur + 4096 + toff3);
        acc[0] = __builtin_amdgcn_mfma_f32_16x16x32_bf16(a, b0, acc[0], 0, 0, 0);
        acc[1] = __builtin_amdgcn_mfma_f32_16x16x32_bf16(a, b1, acc[1], 0, 0, 0);
        acc[2] = __builtin_amdgcn_mfma_f32_16x16x32_bf16(a, b2, acc[2], 0, 0, 0);
        acc[3] = __builtin_amdgcn_mfma_f32_16x16x32_bf16(a, b3, acc[3], 0, 0, 0);
        __syncthreads();
        cur = nxt;
    }
#undef STAGE

    float* dst = relP + (size_t)jc * (B_ * N_ * F_);
#pragma unroll
    for (int cf = 0; cf < 4; ++cf) {
#pragma unroll
        for (int r = 0; r < 4; ++r) {
            int i = it * 64 + isub * 16 + lgrp * 4 + r;
            int f = fh * 64 + cf * 16 + lrow;
            dst[((size_t)b * N_ + i) * F_ + f] = acc[cf][r];
        }
    }
}

// ---------------- k4: epilogue (r12-validated, 2 partials) ----------------
__global__ void __launch_bounds__(512)
k4_epi2(const float* __restrict__ relP, const float* __restrict__ H,
        const unsigned short* __restrict__ SWt, const float* __restrict__ colsum,
        float* __restrict__ out) {
    int bid = blockIdx.x;
    int b  = bid >> 3;
    int it = bid & 7;
    int lane = threadIdx.x & 63;
    int wv   = threadIdx.x >> 6;
    int i0 = it * 64 + (wv >> 1) * 16;
    int f0 = (wv & 1) * 64;
    int lrow = lane & 15, lgrp = lane >> 4;

    float4v accS[4];
#pragma unroll
    for (int i = 0; i < 4; ++i) accS[i] = {0.f, 0.f, 0.f, 0.f};

    const float* Hp = H + ((size_t)b * N_ + i0 + lrow) * F_;
#pragma unroll
    for (int ms = 0; ms < 4; ++ms) {
        int m0 = ms * 32;
        const float* hp = Hp + m0 + lgrp * 8;
        float4v h0 = *(const float4v*)hp;
        float4v h1 = *(const float4v*)(hp + 4);
        short8 a = pack8(h0, h1);
#pragma unroll
        for (int cf = 0; cf < 4; ++cf) {
            const unsigned short* sp = SWt + (f0 + cf * 16 + lrow) * F_ + m0 + lgrp * 8;
            short8 bb = *(const short8*)sp;
            accS[cf] = __builtin_amdgcn_mfma_f32_16x16x32_bf16(a, bb, accS[cf], 0, 0, 0);
        }
    }

    float Dv[4];
#pragma unroll
    for (int r = 0; r < 4; ++r) {
        int i = i0 + lgrp * 4 + r;
        Dv[r] = 1.0f / (colsum[b * N_ + i] + (float)K_);
    }
    const size_t S = (size_t)B_ * N_ * F_;
#pragma unroll
    for (int cf = 0; cf < 4; ++cf) {
#pragma unroll
        for (int r = 0; r < 4; ++r) {
            int i = i0 + lgrp * 4 + r;
            int f = f0 + cf * 16 + lrow;
            size_t idx = ((size_t)b * N_ + i) * F_ + f;
            float v = relP[idx] + relP[idx + S];
            float x = Dv[r] * v + accS[cf][r];
            out[idx] = 1.0f / (1.0f + __expf(-x));
        }
    }
}

// ================= fallback (validated round-5 kernels) =================
__global__ void k1_colsum(const float* __restrict__ E, float* __restrict__ colsum) {
    int bid = blockIdx.x;
    int b   = bid >> 5;
    int jt  = (bid >> 4) & 1;
    int isl = bid & 15;
    int j   = jt * 256 + threadIdx.x;
    int i0  = isl * 32;
    float s0 = 0.f, s1 = 0.f, s2 = 0.f, s3 = 0.f;
#pragma unroll
    for (int k = 0; k < K_; ++k) {
        const float* p = E + ((size_t)((b * K_ + k) * N_ + i0)) * N_ + j;
#pragma unroll 4
        for (int ii = 0; ii < 32; ii += 4) {
            s0 += p[(ii + 0) * N_];
            s1 += p[(ii + 1) * N_];
            s2 += p[(ii + 2) * N_];
            s3 += p[(ii + 3) * N_];
        }
    }
    atomicAdd(&colsum[b * N_ + j], (s0 + s1) + (s2 + s3));
}

__global__ void __launch_bounds__(512)
k3_fuse(const float* __restrict__ E, const float* __restrict__ H,
        const unsigned short* __restrict__ Tt, const unsigned short* __restrict__ SWt,
        const float* __restrict__ colsum, float* __restrict__ out) {
    int bid = blockIdx.x;
    int b  = bid >> 3;
    int it = bid & 7;
    int lane = threadIdx.x & 63;
    int wv   = threadIdx.x >> 6;
    int i0 = it * 64 + (wv >> 1) * 16;
    int f0 = (wv & 1) * 64;
    int lrow = lane & 15, lgrp = lane >> 4;

    float4v accR[4], accS[4];
#pragma unroll
    for (int i = 0; i < 4; ++i) { accR[i] = {0.f, 0.f, 0.f, 0.f}; accS[i] = {0.f, 0.f, 0.f, 0.f}; }

    for (int k = 0; k < K_; ++k) {
        const float* Eb = E + ((size_t)((b * K_ + k) * N_ + i0 + lrow)) * N_;
        const unsigned short* Tb = Tt + ((size_t)b * 512 + k * 128 + f0) * N_;
#pragma unroll 2
        for (int js = 0; js < 16; ++js) {
            int j0 = js * 32;
            const float* ep = Eb + j0 + lgrp * 8;
            float4v e0 = *(const float4v*)ep;
            float4v e1 = *(const float4v*)(ep + 4);
            short8 a = pack8(e0, e1);
#pragma unroll
            for (int cf = 0; cf < 4; ++cf) {
                const unsigned short* tp = Tb + (size_t)(cf * 16 + lrow) * N_ + j0 + lgrp * 8;
                short8 bb = *(const short8*)tp;
                accR[cf] = __builtin_amdgcn_mfma_f32_16x16x32_bf16(a, bb, accR[cf], 0, 0, 0);
            }
        }
    }
    {
        const float* Hp = H + ((size_t)b * N_ + i0 + lrow) * F_;
#pragma unroll
        for (int ms = 0; ms < 4; ++ms) {
            int m0 = ms * 32;
            const float* hp = Hp + m0 + lgrp * 8;
            float4v h0 = *(const float4v*)hp;
            float4v h1 = *(const float4v*)(hp + 4);
            short8 a = pack8(h0, h1);
#pragma unroll
            for (int cf = 0; cf < 4; ++cf) {
                const unsigned short* sp = SWt + (f0 + cf * 16 + lrow) * F_ + m0 + lgrp * 8;
                short8 bb = *(const short8*)sp;
                accS[cf] = __builtin_amdgcn_mfma_f32_16x16x32_bf16(a, bb, accS[cf], 0, 0, 0);
            }
        }
    }
    float Dv[4];
#pragma unroll
    for (int r = 0; r < 4; ++r) {
        int i = i0 + lgrp * 4 + r;
        Dv[r] = 1.0f / (colsum[b * N_ + i] + (float)K_);
    }
#pragma unroll
    for (int cf = 0; cf < 4; ++cf) {
#pragma unroll
        for (int r = 0; r < 4; ++r) {
            int i = i0 + lgrp * 4 + r;
            int f = f0 + cf * 16 + lrow;
            float x = Dv[r] * accR[cf][r] + accS[cf][r];
            out[((size_t)b * N_ + i) * F_ + f] = 1.0f / (1.0f + __expf(-x));
        }
    }
}

extern "C" void kernel_launch(void* const* d_in, const int* in_sizes, int n_in,
                              void* d_out, int out_size, void* d_ws, size_t ws_size,
                              hipStream_t stream) {
    const float* H  = (const float*)d_in[0];
    const float* E  = (const float*)d_in[1];
    const float* RW = (const float*)d_in[2];
    const float* SW = (const float*)d_in[3];
    float* out = (float*)d_out;

    char* ws = (char*)d_ws;
    unsigned short* Wt  = (unsigned short*)(ws);               // 128 KiB
    unsigned short* SWt = (unsigned short*)(ws + 131072);      //  32 KiB
    float* colsum       = (float*)(ws + 163840);               //  64 KiB
    unsigned short* Tt  = (unsigned short*)(ws + 262144);      //  16 MiB
    unsigned short* Ebf = (unsigned short*)(ws + 17039360);    //  64 MiB
    float* relP         = (float*)(ws + 84148224);             //  16 MiB (2 x 8 MiB)
    const size_t WS_NEED = 100925440ull;

    hipMemsetAsync(colsum, 0, B_ * N_ * sizeof(float), stream);
    k0_weights<<<640, 128, 0, stream>>>(RW, SW, Wt, SWt);

    if (ws_size >= WS_NEED) {
        kS_stream<<<16384, 256, 0, stream>>>(E, colsum, Ebf);
        k2v3_expand<<<1024, 256, 0, stream>>>(H, Wt, Tt);
        kB_rel<<<512, 512, 0, stream>>>(Ebf, Tt, relP);
        k4_epi2<<<256, 512, 0, stream>>>(relP, H, SWt, colsum, out);
    } else {
        k1_colsum<<<1024, 256, 0, stream>>>(E, colsum);
        k2v3_expand<<<1024, 256, 0, stream>>>(H, Wt, Tt);
        k3_fuse<<<256, 512, 0, stream>>>(E, H, Tt, SWt, colsum, out);
    }
}